// Round 1
// baseline (176.156 us; speedup 1.0000x reference)
//
#include <hip/hip_runtime.h>
#include <hip/hip_bf16.h>
#include <stdint.h>

// GCN layer: out = segment_sum(x[src], dst) @ W^T + b
// Strategy: y = x @ W^T (bf16 table, 2.56MB, L2-resident) -> CSR counting sort
// of edges by dst -> per-node wave gather-reduce in fp32.

// ---------------- K0: detect whether index buffers are int64 or int32 -------
// If indices are int64 (values < 2^31), every odd 32-bit word is 0.
__global__ void k_detect(const unsigned int* __restrict__ srcw, int* __restrict__ flag) {
    __shared__ unsigned int any;
    if (threadIdx.x == 0) any = 0u;
    __syncthreads();
    unsigned int v = srcw[2 * threadIdx.x + 1];   // words 1,3,...,511
    if (v) atomicOr(&any, 1u);
    __syncthreads();
    if (threadIdx.x == 0) *flag = (any ? 0 : 1);  // 1 => int64
}

// ---------------- K1: canonicalize indices to int32 -------------------------
__global__ void k_convert(const void* __restrict__ srcv, const void* __restrict__ dstv,
                          int* __restrict__ sidx, int* __restrict__ didx,
                          const int* __restrict__ flag, int E) {
    int e = blockIdx.x * 256 + threadIdx.x;
    if (e >= E) return;
    if (*flag) {
        sidx[e] = (int)((const long long*)srcv)[e];
        didx[e] = (int)((const long long*)dstv)[e];
    } else {
        sidx[e] = ((const int*)srcv)[e];
        didx[e] = ((const int*)dstv)[e];
    }
}

// ---------------- K2: y = x @ W^T  (fp32 compute, bf16 store) ---------------
// Block handles 32 nodes. d-tiled (4 tiles of 32). W slice in LDS with XOR
// swizzle (conflict-free), x slice in LDS (broadcast reads). Each thread
// computes a 4-node x 4-output register tile.
__global__ __launch_bounds__(256) void k_xw(const float* __restrict__ x,
                                            const float* __restrict__ W,
                                            __hip_bfloat16* __restrict__ y, int N) {
    __shared__ float Wl[128 * 32];  // Wl[o*32 + (dd ^ (o&31))]
    __shared__ float xs[32 * 32];   // xs[nn*32 + dd]
    int n0 = blockIdx.x * 32;
    int ho = threadIdx.x & 31;   // output group: o = ho + 32k
    int hn = threadIdx.x >> 5;   // node group:  n = n0 + hn*4 + j
    float acc[4][4] = {{0.f}};
    for (int dt = 0; dt < 4; ++dt) {
        __syncthreads();
        for (int i = threadIdx.x; i < 128 * 32; i += 256) {
            int o = i >> 5, dd = i & 31;
            Wl[o * 32 + (dd ^ (o & 31))] = W[o * 128 + dt * 32 + dd];
        }
        for (int i = threadIdx.x; i < 32 * 32; i += 256) {
            int nn = i >> 5, dd = i & 31;
            int n = n0 + nn;
            xs[nn * 32 + dd] = (n < N) ? x[(size_t)n * 128 + dt * 32 + dd] : 0.f;
        }
        __syncthreads();
        for (int dd = 0; dd < 32; ++dd) {
            float w0 = Wl[(ho      ) * 32 + (dd ^ ho)];
            float w1 = Wl[(ho + 32 ) * 32 + (dd ^ ho)];
            float w2 = Wl[(ho + 64 ) * 32 + (dd ^ ho)];
            float w3 = Wl[(ho + 96 ) * 32 + (dd ^ ho)];
#pragma unroll
            for (int j = 0; j < 4; ++j) {
                float xv = xs[(hn * 4 + j) * 32 + dd];
                acc[j][0] = fmaf(xv, w0, acc[j][0]);
                acc[j][1] = fmaf(xv, w1, acc[j][1]);
                acc[j][2] = fmaf(xv, w2, acc[j][2]);
                acc[j][3] = fmaf(xv, w3, acc[j][3]);
            }
        }
    }
    for (int j = 0; j < 4; ++j) {
        int n = n0 + hn * 4 + j;
        if (n >= N) continue;
#pragma unroll
        for (int k = 0; k < 4; ++k)
            y[(size_t)n * 128 + ho + 32 * k] = __float2bfloat16(acc[j][k]);
    }
}

// ---------------- K3: degree histogram ---------------------------------------
__global__ void k_hist(const int* __restrict__ didx, int* __restrict__ deg, int E) {
    int e = blockIdx.x * 256 + threadIdx.x;
    if (e < E) atomicAdd(&deg[didx[e]], 1);
}

// ---------------- K4: exclusive scan (single block) --------------------------
__global__ void k_scan(const int* __restrict__ deg, int* __restrict__ offsets,
                       int* __restrict__ cursor, int N) {
    __shared__ int part[256];
    int t = threadIdx.x;
    int chunk = (N + 255) / 256;
    int beg = t * chunk, endi = beg + chunk;
    if (endi > N) endi = N;
    int s = 0;
    for (int i = beg; i < endi; ++i) s += deg[i];
    part[t] = s;
    __syncthreads();
    if (t == 0) {
        int run = 0;
        for (int i = 0; i < 256; ++i) { int tmp = part[i]; part[i] = run; run += tmp; }
        offsets[N] = run;  // == E
    }
    __syncthreads();
    int run = part[t];
    for (int i = beg; i < endi; ++i) {
        offsets[i] = run;
        cursor[i] = run;
        run += deg[i];
    }
}

// ---------------- K5: scatter edge source ids into dst buckets ---------------
__global__ void k_bucket(const int* __restrict__ sidx, const int* __restrict__ didx,
                         int* __restrict__ cursor, int* __restrict__ bucket, int E) {
    int e = blockIdx.x * 256 + threadIdx.x;
    if (e < E) {
        int pos = atomicAdd(&cursor[didx[e]], 1);
        bucket[pos] = sidx[e];
    }
}

// ---------------- K6: per-node gather-reduce ---------------------------------
// One wave per node; lane owns feature dims (2*lane, 2*lane+1).
__global__ __launch_bounds__(256) void k_gather(const __hip_bfloat162* __restrict__ y2,
                                                const int* __restrict__ offsets,
                                                const int* __restrict__ bucket,
                                                const float* __restrict__ b,
                                                float* __restrict__ out, int N) {
    int n = (blockIdx.x * 256 + threadIdx.x) >> 6;
    int lane = threadIdx.x & 63;
    if (n >= N) return;
    float2 acc = ((const float2*)b)[lane];
    int beg = offsets[n], end = offsets[n + 1];
    for (int i = beg; i < end; i += 64) {
        int cnt = end - i;
        if (cnt > 64) cnt = 64;
        int e = 0;
        if (lane < cnt) e = bucket[i + lane];
#pragma unroll 4
        for (int k = 0; k < cnt; ++k) {
            int s = __shfl(e, k);
            __hip_bfloat162 v = y2[(size_t)s * 64 + lane];
            float2 f = __bfloat1622float2(v);
            acc.x += f.x;
            acc.y += f.y;
        }
    }
    ((float2*)out)[(size_t)n * 64 + lane] = acc;
}

extern "C" void kernel_launch(void* const* d_in, const int* in_sizes, int n_in,
                              void* d_out, int out_size, void* d_ws, size_t ws_size,
                              hipStream_t stream) {
    const float* x = (const float*)d_in[0];
    const void* srcv = d_in[1];
    const void* dstv = d_in[2];
    const float* W = (const float*)d_in[3];
    const float* b = (const float*)d_in[4];
    float* out = (float*)d_out;

    const int D = 128;
    int N = in_sizes[0] / D;
    int E = in_sizes[1];

    char* ws = (char*)d_ws;
    size_t off = 0;
    auto take = [&](size_t bytes) {
        char* p = ws + off;
        off = (off + bytes + 255) & ~(size_t)255;
        return p;
    };
    __hip_bfloat16* y = (__hip_bfloat16*)take((size_t)N * D * 2);
    int* sidx    = (int*)take((size_t)E * 4);
    int* didx    = (int*)take((size_t)E * 4);
    int* bucket  = (int*)take((size_t)E * 4);
    int* deg     = (int*)take((size_t)N * 4);
    int* offsets = (int*)take((size_t)(N + 1) * 4);
    int* cursor  = (int*)take((size_t)N * 4);
    int* flag    = (int*)take(4);

    int eb = (E + 255) / 256;
    hipMemsetAsync(deg, 0, (size_t)N * 4, stream);
    k_detect<<<1, 256, 0, stream>>>((const unsigned int*)srcv, flag);
    k_convert<<<eb, 256, 0, stream>>>(srcv, dstv, sidx, didx, flag, E);
    k_xw<<<(N + 31) / 32, 256, 0, stream>>>(x, W, y, N);
    k_hist<<<eb, 256, 0, stream>>>(didx, deg, E);
    k_scan<<<1, 256, 0, stream>>>(deg, offsets, cursor, N);
    k_bucket<<<eb, 256, 0, stream>>>(sidx, didx, cursor, bucket, E);
    k_gather<<<(N + 3) / 4, 256, 0, stream>>>((const __hip_bfloat162*)y, offsets, bucket,
                                              b, out, N);
}

// Round 2
// 103.905 us; speedup vs baseline: 1.6954x; 1.6954x over previous
//
#include <hip/hip_runtime.h>
#include <hip/hip_bf16.h>
#include <stdint.h>

// GCN layer: out = segment_sum(x[src], dst) @ W^T + b
// y = x @ W^T (bf16 table, 2.56MB, L2-resident) -> atomic-free counting sort
// of edges by dst (LDS histograms, hist-matrix scan) -> per-node wave
// gather-reduce in fp32.

#define NBLK 128          // counting-sort partitions
#define MAXBINS 10240     // LDS histogram capacity (N must be <= this)

// ---------------- K0: detect whether index buffers are int64 or int32 -------
__global__ void k_detect(const unsigned int* __restrict__ srcw, int* __restrict__ flag) {
    __shared__ unsigned int any;
    if (threadIdx.x == 0) any = 0u;
    __syncthreads();
    unsigned int v = srcw[2 * threadIdx.x + 1];   // high words if int64
    if (v) atomicOr(&any, 1u);
    __syncthreads();
    if (threadIdx.x == 0) *flag = (any ? 0 : 1);  // 1 => int64
}

// ---------------- K1: per-block LDS histogram of dst -------------------------
__global__ __launch_bounds__(1024) void k_hist(const void* __restrict__ dstv,
                                               const int* __restrict__ flag,
                                               int* __restrict__ ghist,
                                               int E, int N, int C) {
    __shared__ int h[MAXBINS];
    for (int i = threadIdx.x; i < N; i += 1024) h[i] = 0;
    __syncthreads();
    int beg = blockIdx.x * C;
    int end = min(E, beg + C);
    if (*flag) {
        const long long* d = (const long long*)dstv;
        for (int e = beg + threadIdx.x; e < end; e += 1024)
            atomicAdd(&h[(int)d[e]], 1);
    } else {
        const int* d = (const int*)dstv;
        for (int e = beg + threadIdx.x; e < end; e += 1024)
            atomicAdd(&h[d[e]], 1);
    }
    __syncthreads();
    int* row = ghist + (size_t)blockIdx.x * N;
    for (int i = threadIdx.x; i < N; i += 1024) row[i] = h[i];
}

// ---------------- K2: per-bin column sum -------------------------------------
__global__ void k_colsum(const int* __restrict__ ghist, int* __restrict__ deg, int N) {
    int b = blockIdx.x * 256 + threadIdx.x;
    if (b >= N) return;
    int s = 0;
#pragma unroll 16
    for (int k = 0; k < NBLK; ++k) s += ghist[(size_t)k * N + b];
    deg[b] = s;
}

// ---------------- K3: exclusive scan of deg -> offsets (single block) --------
__global__ __launch_bounds__(1024) void k_scan(const int* __restrict__ deg,
                                               int* __restrict__ offsets, int N, int E) {
    __shared__ int part[1024];
    int t = threadIdx.x;
    int chunk = (N + 1023) / 1024;
    int beg = t * chunk, end = min(N, beg + chunk);
    int s = 0;
    for (int i = beg; i < end; ++i) s += deg[i];
    part[t] = s;
    for (int off = 1; off < 1024; off <<= 1) {
        __syncthreads();
        int v = (t >= off) ? part[t - off] : 0;
        __syncthreads();
        part[t] += v;
    }
    __syncthreads();
    int run = (t == 0) ? 0 : part[t - 1];
    for (int i = beg; i < end; ++i) { offsets[i] = run; run += deg[i]; }
    if (t == 0) offsets[N] = E;
}

// ---------------- K4: column exclusive scan -> per-block bases in ghist ------
__global__ void k_colbase(int* __restrict__ ghist, const int* __restrict__ offsets, int N) {
    int b = blockIdx.x * 256 + threadIdx.x;
    if (b >= N) return;
    int run = offsets[b];
#pragma unroll 16
    for (int k = 0; k < NBLK; ++k) {
        size_t idx = (size_t)k * N + b;
        int tmp = ghist[idx];
        ghist[idx] = run;
        run += tmp;
    }
}

// ---------------- K5: scatter src ids into dst buckets (LDS cursor) ----------
__global__ __launch_bounds__(1024) void k_scatter(const void* __restrict__ srcv,
                                                  const void* __restrict__ dstv,
                                                  const int* __restrict__ flag,
                                                  const int* __restrict__ ghist,
                                                  int* __restrict__ bucket,
                                                  int E, int N, int C) {
    __shared__ int cur[MAXBINS];
    const int* row = ghist + (size_t)blockIdx.x * N;
    for (int i = threadIdx.x; i < N; i += 1024) cur[i] = row[i];
    __syncthreads();
    int beg = blockIdx.x * C;
    int end = min(E, beg + C);
    if (*flag) {
        const long long* s = (const long long*)srcv;
        const long long* d = (const long long*)dstv;
        for (int e = beg + threadIdx.x; e < end; e += 1024) {
            int pos = atomicAdd(&cur[(int)d[e]], 1);
            bucket[pos] = (int)s[e];
        }
    } else {
        const int* s = (const int*)srcv;
        const int* d = (const int*)dstv;
        for (int e = beg + threadIdx.x; e < end; e += 1024) {
            int pos = atomicAdd(&cur[d[e]], 1);
            bucket[pos] = s[e];
        }
    }
}

// ---------------- K6: y = x @ W^T  (fp32 compute, bf16 store) ---------------
__global__ __launch_bounds__(256) void k_xw(const float* __restrict__ x,
                                            const float* __restrict__ W,
                                            __hip_bfloat16* __restrict__ y, int N) {
    __shared__ float Wl[128 * 32];  // Wl[o*32 + (dd ^ (o&31))]
    __shared__ float xs[32 * 32];   // xs[nn*32 + dd]
    int n0 = blockIdx.x * 32;
    int ho = threadIdx.x & 31;   // output group: o = ho + 32k
    int hn = threadIdx.x >> 5;   // node group:  n = n0 + hn*4 + j
    float acc[4][4] = {{0.f}};
    for (int dt = 0; dt < 4; ++dt) {
        __syncthreads();
        for (int i = threadIdx.x; i < 128 * 32; i += 256) {
            int o = i >> 5, dd = i & 31;
            Wl[o * 32 + (dd ^ (o & 31))] = W[o * 128 + dt * 32 + dd];
        }
        for (int i = threadIdx.x; i < 32 * 32; i += 256) {
            int nn = i >> 5, dd = i & 31;
            int n = n0 + nn;
            xs[nn * 32 + dd] = (n < N) ? x[(size_t)n * 128 + dt * 32 + dd] : 0.f;
        }
        __syncthreads();
        for (int dd = 0; dd < 32; ++dd) {
            float w0 = Wl[(ho      ) * 32 + (dd ^ ho)];
            float w1 = Wl[(ho + 32 ) * 32 + (dd ^ ho)];
            float w2 = Wl[(ho + 64 ) * 32 + (dd ^ ho)];
            float w3 = Wl[(ho + 96 ) * 32 + (dd ^ ho)];
#pragma unroll
            for (int j = 0; j < 4; ++j) {
                float xv = xs[(hn * 4 + j) * 32 + dd];
                acc[j][0] = fmaf(xv, w0, acc[j][0]);
                acc[j][1] = fmaf(xv, w1, acc[j][1]);
                acc[j][2] = fmaf(xv, w2, acc[j][2]);
                acc[j][3] = fmaf(xv, w3, acc[j][3]);
            }
        }
    }
    for (int j = 0; j < 4; ++j) {
        int n = n0 + hn * 4 + j;
        if (n >= N) continue;
#pragma unroll
        for (int k = 0; k < 4; ++k)
            y[(size_t)n * 128 + ho + 32 * k] = __float2bfloat16(acc[j][k]);
    }
}

// ---------------- K7: per-node gather-reduce ---------------------------------
// One wave per node; lane owns feature dims (2*lane, 2*lane+1).
__global__ __launch_bounds__(256) void k_gather(const __hip_bfloat162* __restrict__ y2,
                                                const int* __restrict__ offsets,
                                                const int* __restrict__ bucket,
                                                const float* __restrict__ b,
                                                float* __restrict__ out, int N) {
    int n = (blockIdx.x * 256 + threadIdx.x) >> 6;
    int lane = threadIdx.x & 63;
    if (n >= N) return;
    float2 acc = ((const float2*)b)[lane];
    int beg = offsets[n], end = offsets[n + 1];
    for (int i = beg; i < end; i += 64) {
        int cnt = end - i;
        if (cnt > 64) cnt = 64;
        int e = 0;
        if (lane < cnt) e = bucket[i + lane];
#pragma unroll 4
        for (int k = 0; k < cnt; ++k) {
            int s = __shfl(e, k);
            __hip_bfloat162 v = y2[(size_t)s * 64 + lane];
            float2 f = __bfloat1622float2(v);
            acc.x += f.x;
            acc.y += f.y;
        }
    }
    ((float2*)out)[(size_t)n * 64 + lane] = acc;
}

extern "C" void kernel_launch(void* const* d_in, const int* in_sizes, int n_in,
                              void* d_out, int out_size, void* d_ws, size_t ws_size,
                              hipStream_t stream) {
    const float* x = (const float*)d_in[0];
    const void* srcv = d_in[1];
    const void* dstv = d_in[2];
    const float* W = (const float*)d_in[3];
    const float* b = (const float*)d_in[4];
    float* out = (float*)d_out;

    const int D = 128;
    int N = in_sizes[0] / D;
    int E = in_sizes[1];
    int C = (E + NBLK - 1) / NBLK;

    char* ws = (char*)d_ws;
    size_t off = 0;
    auto take = [&](size_t bytes) {
        char* p = ws + off;
        off = (off + bytes + 255) & ~(size_t)255;
        return p;
    };
    __hip_bfloat16* y = (__hip_bfloat16*)take((size_t)N * D * 2);
    int* bucket  = (int*)take((size_t)E * 4);
    int* ghist   = (int*)take((size_t)NBLK * N * 4);
    int* deg     = (int*)take((size_t)N * 4);
    int* offsets = (int*)take((size_t)(N + 1) * 4);
    int* flag    = (int*)take(4);

    int nb256 = (N + 255) / 256;
    k_detect<<<1, 256, 0, stream>>>((const unsigned int*)srcv, flag);
    k_xw<<<(N + 31) / 32, 256, 0, stream>>>(x, W, y, N);
    k_hist<<<NBLK, 1024, 0, stream>>>(dstv, flag, ghist, E, N, C);
    k_colsum<<<nb256, 256, 0, stream>>>(ghist, deg, N);
    k_scan<<<1, 1024, 0, stream>>>(deg, offsets, N, E);
    k_colbase<<<nb256, 256, 0, stream>>>(ghist, offsets, N);
    k_scatter<<<NBLK, 1024, 0, stream>>>(srcv, dstv, flag, ghist, bucket, E, N, C);
    k_gather<<<(N + 3) / 4, 256, 0, stream>>>((const __hip_bfloat162*)y, offsets, bucket,
                                              b, out, N);
}

// Round 3
// 71.387 us; speedup vs baseline: 2.4676x; 1.4555x over previous
//
#include <hip/hip_runtime.h>
#include <hip/hip_bf16.h>
#include <stdint.h>

// GCN layer: out = segment_sum(x[src], dst) @ W^T + b
// y = x @ W^T via bf16 MFMA (bf16 table, 2.56MB, L2-resident) -> atomic-free
// counting sort of edges by dst (LDS histograms, hist-matrix scan) ->
// per-node wave gather-reduce, 4 edges/iter, 16B/lane loads, fp32 accum.

#define NBLK 128          // counting-sort partitions
#define MAXBINS 10240     // LDS histogram capacity (N must be <= this)

typedef __attribute__((ext_vector_type(8))) short bf16x8;
typedef __attribute__((ext_vector_type(4))) float f32x4;
typedef __attribute__((ext_vector_type(8))) unsigned short u16x8;

static __device__ inline unsigned short f2bf(float f) {   // RNE f32 -> bf16
    unsigned int u = __float_as_uint(f);
    u += 0x7fffu + ((u >> 16) & 1u);
    return (unsigned short)(u >> 16);
}

// ---------------- K0: detect whether index buffers are int64 or int32 -------
__global__ void k_detect(const unsigned int* __restrict__ srcw, int* __restrict__ flag) {
    __shared__ unsigned int any;
    if (threadIdx.x == 0) any = 0u;
    __syncthreads();
    unsigned int v = srcw[2 * threadIdx.x + 1];   // high words if int64
    if (v) atomicOr(&any, 1u);
    __syncthreads();
    if (threadIdx.x == 0) *flag = (any ? 0 : 1);  // 1 => int64
}

// ---------------- K1: per-block LDS histogram of dst (u16 rows) --------------
__global__ __launch_bounds__(1024) void k_hist(const void* __restrict__ dstv,
                                               const int* __restrict__ flag,
                                               unsigned short* __restrict__ ghist,
                                               int E, int N, int C) {
    __shared__ int h[MAXBINS];
    for (int i = threadIdx.x; i < N; i += 1024) h[i] = 0;
    __syncthreads();
    int beg = blockIdx.x * C;
    int end = min(E, beg + C);
    if (*flag) {
        const long long* d = (const long long*)dstv;
        for (int e = beg + threadIdx.x; e < end; e += 1024)
            atomicAdd(&h[(int)d[e]], 1);
    } else {
        const int* d = (const int*)dstv;
        for (int e = beg + threadIdx.x; e < end; e += 1024)
            atomicAdd(&h[d[e]], 1);
    }
    __syncthreads();
    unsigned short* row = ghist + (size_t)blockIdx.x * N;
    for (int i = threadIdx.x; i < N; i += 1024) row[i] = (unsigned short)h[i];
}

// ---------------- K2: per-bin column sum -------------------------------------
__global__ void k_colsum(const unsigned short* __restrict__ ghist,
                         int* __restrict__ deg, int N) {
    int b = blockIdx.x * 256 + threadIdx.x;
    if (b >= N) return;
    int s = 0;
#pragma unroll 16
    for (int k = 0; k < NBLK; ++k) s += (int)ghist[(size_t)k * N + b];
    deg[b] = s;
}

// ---------------- K3: exclusive scan of deg -> offsets (single block) --------
__global__ __launch_bounds__(1024) void k_scan(const int* __restrict__ deg,
                                               int* __restrict__ offsets, int N, int E) {
    __shared__ int part[1024];
    int t = threadIdx.x;
    int chunk = (N + 1023) / 1024;
    int beg = t * chunk, end = min(N, beg + chunk);
    int s = 0;
    for (int i = beg; i < end; ++i) s += deg[i];
    part[t] = s;
    for (int off = 1; off < 1024; off <<= 1) {
        __syncthreads();
        int v = (t >= off) ? part[t - off] : 0;
        __syncthreads();
        part[t] += v;
    }
    __syncthreads();
    int run = (t == 0) ? 0 : part[t - 1];
    for (int i = beg; i < end; ++i) { offsets[i] = run; run += deg[i]; }
    if (t == 0) offsets[N] = E;
}

// ---------------- K4: column exclusive scan -> per-block int bases -----------
__global__ void k_colbase(const unsigned short* __restrict__ ghist,
                          int* __restrict__ gbase,
                          const int* __restrict__ offsets, int N) {
    int b = blockIdx.x * 256 + threadIdx.x;
    if (b >= N) return;
    int run = offsets[b];
#pragma unroll 16
    for (int k = 0; k < NBLK; ++k) {
        size_t idx = (size_t)k * N + b;
        gbase[idx] = run;
        run += (int)ghist[idx];
    }
}

// ---------------- K5: scatter src ids into dst buckets (LDS cursor) ----------
__global__ __launch_bounds__(1024) void k_scatter(const void* __restrict__ srcv,
                                                  const void* __restrict__ dstv,
                                                  const int* __restrict__ flag,
                                                  const int* __restrict__ gbase,
                                                  int* __restrict__ bucket,
                                                  int E, int N, int C) {
    __shared__ int cur[MAXBINS];
    const int* row = gbase + (size_t)blockIdx.x * N;
    for (int i = threadIdx.x; i < N; i += 1024) cur[i] = row[i];
    __syncthreads();
    int beg = blockIdx.x * C;
    int end = min(E, beg + C);
    if (*flag) {
        const long long* s = (const long long*)srcv;
        const long long* d = (const long long*)dstv;
        for (int e = beg + threadIdx.x; e < end; e += 1024) {
            int pos = atomicAdd(&cur[(int)d[e]], 1);
            bucket[pos] = (int)s[e];
        }
    } else {
        const int* s = (const int*)srcv;
        const int* d = (const int*)dstv;
        for (int e = beg + threadIdx.x; e < end; e += 1024) {
            int pos = atomicAdd(&cur[d[e]], 1);
            bucket[pos] = s[e];
        }
    }
}

// ---------------- K6: y = x @ W^T via MFMA (fp32 in, bf16 table out) ---------
// One wave per 16 nodes. A frag: x[m0+lane%16][k], k=(lane/16)*8+j (bf16x8).
// B frag: W[o0+lane%16][k] == B[k][o]. D: col=lane&15 (o), row=(lane>>4)*4+reg.
__global__ __launch_bounds__(256) void k_xw(const float* __restrict__ x,
                                            const float* __restrict__ W,
                                            unsigned short* __restrict__ y, int N) {
    int wid = blockIdx.x * 4 + (threadIdx.x >> 6);
    int lane = threadIdx.x & 63;
    int m0 = wid * 16;
    if (m0 >= N) return;
    int r = lane & 15, hi = lane >> 4;
    int mr = m0 + r; if (mr >= N) mr = N - 1;   // clamp (N%16==0 -> no-op)
    bf16x8 a[4];
    const float* xr = x + (size_t)mr * 128 + hi * 8;
#pragma unroll
    for (int kt = 0; kt < 4; ++kt) {
        float4 f0 = *(const float4*)(xr + kt * 32);
        float4 f1 = *(const float4*)(xr + kt * 32 + 4);
        unsigned short* ap = (unsigned short*)&a[kt];
        ap[0] = f2bf(f0.x); ap[1] = f2bf(f0.y); ap[2] = f2bf(f0.z); ap[3] = f2bf(f0.w);
        ap[4] = f2bf(f1.x); ap[5] = f2bf(f1.y); ap[6] = f2bf(f1.z); ap[7] = f2bf(f1.w);
    }
#pragma unroll 2
    for (int ot = 0; ot < 8; ++ot) {
        f32x4 acc = {0.f, 0.f, 0.f, 0.f};
        const float* wr = W + (size_t)(ot * 16 + r) * 128 + hi * 8;
#pragma unroll
        for (int kt = 0; kt < 4; ++kt) {
            float4 f0 = *(const float4*)(wr + kt * 32);
            float4 f1 = *(const float4*)(wr + kt * 32 + 4);
            bf16x8 bf;
            unsigned short* bp = (unsigned short*)&bf;
            bp[0] = f2bf(f0.x); bp[1] = f2bf(f0.y); bp[2] = f2bf(f0.z); bp[3] = f2bf(f0.w);
            bp[4] = f2bf(f1.x); bp[5] = f2bf(f1.y); bp[6] = f2bf(f1.z); bp[7] = f2bf(f1.w);
            acc = __builtin_amdgcn_mfma_f32_16x16x32_bf16(a[kt], bf, acc, 0, 0, 0);
        }
#pragma unroll
        for (int reg = 0; reg < 4; ++reg) {
            int m = m0 + hi * 4 + reg;
            if (m < N) y[(size_t)m * 128 + ot * 16 + r] = f2bf(acc[reg]);
        }
    }
}

// ---------------- K7: per-node gather-reduce, 4 edges/iter -------------------
// One wave per node. g=lane>>4 picks edge-in-quad, r=lane&15 owns dims r*8..r*8+7.
__global__ __launch_bounds__(256) void k_gather(const unsigned short* __restrict__ y,
                                                const int* __restrict__ offsets,
                                                const int* __restrict__ bucket,
                                                const float* __restrict__ b,
                                                float* __restrict__ out, int N) {
    int n = (blockIdx.x * 256 + threadIdx.x) >> 6;
    int lane = threadIdx.x & 63;
    if (n >= N) return;
    int r = lane & 15, g = lane >> 4;
    float acc[8] = {0.f, 0.f, 0.f, 0.f, 0.f, 0.f, 0.f, 0.f};
    const u16x8* yp = (const u16x8*)y;   // row = 16 u16x8 chunks
    int beg = offsets[n], end = offsets[n + 1];
    for (int i = beg; i < end; i += 64) {
        int cnt = end - i;
        if (cnt > 64) cnt = 64;
        int e = bucket[i + (lane < cnt ? lane : 0)];
        int nb = cnt >> 2;
        for (int k = 0; k < nb; ++k) {
            int s = __shfl(e, 4 * k + g);
            u16x8 v = yp[(size_t)s * 16 + r];
#pragma unroll
            for (int j = 0; j < 8; ++j)
                acc[j] += __uint_as_float(((unsigned int)v[j]) << 16);
        }
        int base = nb << 2;
        if (base < cnt) {
            int idx = base + g;
            int s = __shfl(e, idx < cnt ? idx : 0);
            if (idx < cnt) {
                u16x8 v = yp[(size_t)s * 16 + r];
#pragma unroll
                for (int j = 0; j < 8; ++j)
                    acc[j] += __uint_as_float(((unsigned int)v[j]) << 16);
            }
        }
    }
    // combine the 4 edge-groups
#pragma unroll
    for (int j = 0; j < 8; ++j) {
        acc[j] += __shfl_xor(acc[j], 16);
        acc[j] += __shfl_xor(acc[j], 32);
    }
    if (lane < 16) {
        float4 b0 = ((const float4*)b)[r * 2];
        float4 b1 = ((const float4*)b)[r * 2 + 1];
        float4 o0 = {acc[0] + b0.x, acc[1] + b0.y, acc[2] + b0.z, acc[3] + b0.w};
        float4 o1 = {acc[4] + b1.x, acc[5] + b1.y, acc[6] + b1.z, acc[7] + b1.w};
        float4* op = (float4*)(out + (size_t)n * 128 + r * 8);
        op[0] = o0;
        op[1] = o1;
    }
}

extern "C" void kernel_launch(void* const* d_in, const int* in_sizes, int n_in,
                              void* d_out, int out_size, void* d_ws, size_t ws_size,
                              hipStream_t stream) {
    const float* x = (const float*)d_in[0];
    const void* srcv = d_in[1];
    const void* dstv = d_in[2];
    const float* W = (const float*)d_in[3];
    const float* b = (const float*)d_in[4];
    float* out = (float*)d_out;

    const int D = 128;
    int N = in_sizes[0] / D;
    int E = in_sizes[1];
    int C = (E + NBLK - 1) / NBLK;

    char* ws = (char*)d_ws;
    size_t off = 0;
    auto take = [&](size_t bytes) {
        char* p = ws + off;
        off = (off + bytes + 255) & ~(size_t)255;
        return p;
    };
    unsigned short* y       = (unsigned short*)take((size_t)N * D * 2);
    int* bucket             = (int*)take((size_t)E * 4);
    unsigned short* ghist   = (unsigned short*)take((size_t)NBLK * N * 2);
    int* gbase              = (int*)take((size_t)NBLK * N * 4);
    int* deg                = (int*)take((size_t)N * 4);
    int* offsets            = (int*)take((size_t)(N + 1) * 4);
    int* flag               = (int*)take(4);

    int nb256 = (N + 255) / 256;
    int nwaves = (N + 15) / 16;
    k_detect<<<1, 256, 0, stream>>>((const unsigned int*)srcv, flag);
    k_xw<<<(nwaves + 3) / 4, 256, 0, stream>>>(x, W, y, N);
    k_hist<<<NBLK, 1024, 0, stream>>>(dstv, flag, ghist, E, N, C);
    k_colsum<<<nb256, 256, 0, stream>>>(ghist, deg, N);
    k_scan<<<1, 1024, 0, stream>>>(deg, offsets, N, E);
    k_colbase<<<nb256, 256, 0, stream>>>(ghist, gbase, offsets, N);
    k_scatter<<<NBLK, 1024, 0, stream>>>(srcv, dstv, flag, gbase, bucket, E, N, C);
    k_gather<<<(N + 3) / 4, 256, 0, stream>>>(y, offsets, bucket, b, out, N);
}

// Round 4
// 59.740 us; speedup vs baseline: 2.9487x; 1.1950x over previous
//
#include <hip/hip_runtime.h>
#include <hip/hip_bf16.h>
#include <stdint.h>

// GCN layer: out = segment_sum(x[src], dst) @ W^T + b
// Pipeline: prep (idx-dtype detect + W->bf16) -> fused {y=x@W^T via MFMA |
// per-partition LDS hist of dst} -> 3-level scan -> LDS-cursor scatter ->
// per-node wave gather-reduce (4 edges/iter, 16B/lane, fp32 accum).

#define NBLK 128          // counting-sort partitions
#define MAXBINS 10240     // LDS histogram capacity (N must be <= this)

typedef __attribute__((ext_vector_type(8))) short bf16x8;
typedef __attribute__((ext_vector_type(4))) float f32x4;
typedef __attribute__((ext_vector_type(8))) unsigned short u16x8;

static __device__ inline unsigned short f2bf(float f) {   // RNE f32 -> bf16
    unsigned int u = __float_as_uint(f);
    u += 0x7fffu + ((u >> 16) & 1u);
    return (unsigned short)(u >> 16);
}

// ---- K0: block 0 detects int64-vs-int32 indices; blocks 1.. convert W->bf16
__global__ __launch_bounds__(256) void k_prep(const unsigned int* __restrict__ srcw,
                                              int* __restrict__ flag,
                                              const float* __restrict__ W,
                                              unsigned short* __restrict__ Wb, int WE) {
    if (blockIdx.x == 0) {
        __shared__ unsigned int any;
        if (threadIdx.x == 0) any = 0u;
        __syncthreads();
        unsigned int v = srcw[2 * threadIdx.x + 1];   // high words if int64
        if (v) atomicOr(&any, 1u);
        __syncthreads();
        if (threadIdx.x == 0) *flag = (any ? 0 : 1);  // 1 => int64
    } else {
        int i = (blockIdx.x - 1) * 1024 + threadIdx.x * 4;
        if (i + 3 < WE) {
            float4 f = *(const float4*)(W + i);
            ushort4 o = {f2bf(f.x), f2bf(f.y), f2bf(f.z), f2bf(f.w)};
            *(ushort4*)(Wb + i) = o;
        }
    }
}

// ---- K1 fused: blocks [0,xwb) do y = x@W^T (MFMA); blocks [xwb,..) do the
// per-partition LDS histogram of dst. Independent work, one launch.
__global__ __launch_bounds__(256) void k_fused(const float* __restrict__ x,
                                               const unsigned short* __restrict__ Wb,
                                               unsigned short* __restrict__ y,
                                               int N, int xwb,
                                               const void* __restrict__ dstv,
                                               const int* __restrict__ flag,
                                               unsigned short* __restrict__ ghist,
                                               int E, int C) {
    __shared__ int h[MAXBINS];
    if ((int)blockIdx.x < xwb) {
        // ---- y = x @ W^T. One wave per 16 nodes.
        // A frag: x[m0+lane%16][(lane/16)*8+j]; B frag: W[o0+lane%16][k].
        // D: col=lane&15 (o), row=(lane>>4)*4+reg (m).
        int wid = blockIdx.x * 4 + (threadIdx.x >> 6);
        int lane = threadIdx.x & 63;
        int m0 = wid * 16;
        if (m0 >= N) return;
        int r = lane & 15, hi = lane >> 4;
        int mr = m0 + r; if (mr >= N) mr = N - 1;
        bf16x8 a[4];
        const float* xr = x + (size_t)mr * 128 + hi * 8;
#pragma unroll
        for (int kt = 0; kt < 4; ++kt) {
            float4 f0 = *(const float4*)(xr + kt * 32);
            float4 f1 = *(const float4*)(xr + kt * 32 + 4);
            unsigned short* ap = (unsigned short*)&a[kt];
            ap[0] = f2bf(f0.x); ap[1] = f2bf(f0.y); ap[2] = f2bf(f0.z); ap[3] = f2bf(f0.w);
            ap[4] = f2bf(f1.x); ap[5] = f2bf(f1.y); ap[6] = f2bf(f1.z); ap[7] = f2bf(f1.w);
        }
#pragma unroll 2
        for (int ot = 0; ot < 8; ++ot) {
            f32x4 acc = {0.f, 0.f, 0.f, 0.f};
            const unsigned short* wr = Wb + (size_t)(ot * 16 + r) * 128 + hi * 8;
#pragma unroll
            for (int kt = 0; kt < 4; ++kt) {
                bf16x8 bf = *(const bf16x8*)(wr + kt * 32);
                acc = __builtin_amdgcn_mfma_f32_16x16x32_bf16(a[kt], bf, acc, 0, 0, 0);
            }
#pragma unroll
            for (int reg = 0; reg < 4; ++reg) {
                int m = m0 + hi * 4 + reg;
                if (m < N) y[(size_t)m * 128 + ot * 16 + r] = f2bf(acc[reg]);
            }
        }
    } else {
        int bid = blockIdx.x - xwb;
        for (int i = threadIdx.x; i < N; i += 256) h[i] = 0;
        __syncthreads();
        int beg = bid * C;
        int end = min(E, beg + C);
        if (*flag) {
            const long long* d = (const long long*)dstv;
            for (int e = beg + threadIdx.x; e < end; e += 256)
                atomicAdd(&h[(int)d[e]], 1);
        } else {
            const int* d = (const int*)dstv;
            for (int e = beg + threadIdx.x; e < end; e += 256)
                atomicAdd(&h[d[e]], 1);
        }
        __syncthreads();
        unsigned short* row = ghist + (size_t)bid * N;
        for (int i = threadIdx.x; i < N; i += 256) row[i] = (unsigned short)h[i];
    }
}

// ---- K2: column sums + block-local exclusive scan (offsets pre-base) --------
__global__ __launch_bounds__(256) void k_colsum(const unsigned short* __restrict__ ghist,
                                                int* __restrict__ offsets,
                                                int* __restrict__ psum, int N) {
    __shared__ int part[256];
    int b = blockIdx.x * 256 + threadIdx.x;
    int s = 0;
    if (b < N) {
#pragma unroll 16
        for (int k = 0; k < NBLK; ++k) s += (int)ghist[(size_t)k * N + b];
    }
    part[threadIdx.x] = s;
    for (int off = 1; off < 256; off <<= 1) {
        __syncthreads();
        int v = (threadIdx.x >= (unsigned)off) ? part[threadIdx.x - off] : 0;
        __syncthreads();
        part[threadIdx.x] += v;
    }
    __syncthreads();
    if (b < N) offsets[b] = part[threadIdx.x] - s;   // local exclusive
    if (threadIdx.x == 255) psum[blockIdx.x] = part[255];
}

// ---- K3: tiny scan of the 40 block totals (one wave) ------------------------
__global__ void k_pscan(int* __restrict__ psum, int* __restrict__ offsets,
                        int NB, int N, int E) {
    int t = threadIdx.x;
    int v = (t < NB) ? psum[t] : 0;
    int incl = v;
    for (int off = 1; off < 64; off <<= 1) {
        int u = __shfl_up(incl, off);
        if (t >= off) incl += u;
    }
    if (t < NB) psum[t] = incl - v;   // exclusive block base
    if (t == 0) offsets[N] = E;
}

// ---- K4: finalize offsets + column exclusive scan -> per-block bases --------
__global__ __launch_bounds__(256) void k_colbase(const unsigned short* __restrict__ ghist,
                                                 int* __restrict__ gbase,
                                                 int* __restrict__ offsets,
                                                 const int* __restrict__ psum, int N) {
    int b = blockIdx.x * 256 + threadIdx.x;
    if (b >= N) return;
    int run = offsets[b] + psum[blockIdx.x];
    offsets[b] = run;
#pragma unroll 16
    for (int k = 0; k < NBLK; ++k) {
        size_t idx = (size_t)k * N + b;
        gbase[idx] = run;
        run += (int)ghist[idx];
    }
}

// ---- K5: scatter src ids into dst buckets (LDS cursor, atomic-free global) --
__global__ __launch_bounds__(1024) void k_scatter(const void* __restrict__ srcv,
                                                  const void* __restrict__ dstv,
                                                  const int* __restrict__ flag,
                                                  const int* __restrict__ gbase,
                                                  int* __restrict__ bucket,
                                                  int E, int N, int C) {
    __shared__ int cur[MAXBINS];
    const int* row = gbase + (size_t)blockIdx.x * N;
    for (int i = threadIdx.x; i < N; i += 1024) cur[i] = row[i];
    __syncthreads();
    int beg = blockIdx.x * C;
    int end = min(E, beg + C);
    if (*flag) {
        const long long* s = (const long long*)srcv;
        const long long* d = (const long long*)dstv;
        for (int e = beg + threadIdx.x; e < end; e += 1024) {
            int pos = atomicAdd(&cur[(int)d[e]], 1);
            bucket[pos] = (int)s[e];
        }
    } else {
        const int* s = (const int*)srcv;
        const int* d = (const int*)dstv;
        for (int e = beg + threadIdx.x; e < end; e += 1024) {
            int pos = atomicAdd(&cur[d[e]], 1);
            bucket[pos] = s[e];
        }
    }
}

// ---- K6: per-node gather-reduce, 4 edges/iter, unroll-4 load pipeline -------
__global__ __launch_bounds__(256) void k_gather(const unsigned short* __restrict__ y,
                                                const int* __restrict__ offsets,
                                                const int* __restrict__ bucket,
                                                const float* __restrict__ b,
                                                float* __restrict__ out, int N, int E) {
    int n = (blockIdx.x * 256 + threadIdx.x) >> 6;
    int lane = threadIdx.x & 63;
    if (n >= N) return;
    int r = lane & 15, g = lane >> 4;
    float acc[8] = {0.f, 0.f, 0.f, 0.f, 0.f, 0.f, 0.f, 0.f};
    const u16x8* yp = (const u16x8*)y;   // row = 16 u16x8 chunks
    int beg = offsets[n], end = offsets[n + 1];
    for (int i = beg; i < end; i += 64) {
        int cnt = end - i;
        if (cnt > 64) cnt = 64;
        int ei = i + lane; if (ei > E - 1) ei = E - 1;
        int e = bucket[ei];
        int nb = cnt >> 2;
#pragma unroll 4
        for (int k = 0; k < nb; ++k) {
            int s = __shfl(e, 4 * k + g);
            u16x8 v = yp[(size_t)s * 16 + r];
#pragma unroll
            for (int j = 0; j < 8; ++j)
                acc[j] += __uint_as_float(((unsigned int)v[j]) << 16);
        }
        int base = nb << 2;
        if (base < cnt) {
            int idx = base + g;
            int s = __shfl(e, idx < cnt ? idx : 0);
            if (idx < cnt) {
                u16x8 v = yp[(size_t)s * 16 + r];
#pragma unroll
                for (int j = 0; j < 8; ++j)
                    acc[j] += __uint_as_float(((unsigned int)v[j]) << 16);
            }
        }
    }
#pragma unroll
    for (int j = 0; j < 8; ++j) {
        acc[j] += __shfl_xor(acc[j], 16);
        acc[j] += __shfl_xor(acc[j], 32);
    }
    if (lane < 16) {
        float4 b0 = ((const float4*)b)[r * 2];
        float4 b1 = ((const float4*)b)[r * 2 + 1];
        float4 o0 = {acc[0] + b0.x, acc[1] + b0.y, acc[2] + b0.z, acc[3] + b0.w};
        float4 o1 = {acc[4] + b1.x, acc[5] + b1.y, acc[6] + b1.z, acc[7] + b1.w};
        float4* op = (float4*)(out + (size_t)n * 128 + r * 8);
        op[0] = o0;
        op[1] = o1;
    }
}

extern "C" void kernel_launch(void* const* d_in, const int* in_sizes, int n_in,
                              void* d_out, int out_size, void* d_ws, size_t ws_size,
                              hipStream_t stream) {
    const float* x = (const float*)d_in[0];
    const void* srcv = d_in[1];
    const void* dstv = d_in[2];
    const float* W = (const float*)d_in[3];
    const float* b = (const float*)d_in[4];
    float* out = (float*)d_out;

    const int D = 128;
    int N = in_sizes[0] / D;
    int E = in_sizes[1];
    int WE = in_sizes[3];                 // 128*128
    int C = (E + NBLK - 1) / NBLK;

    char* ws = (char*)d_ws;
    size_t off = 0;
    auto take = [&](size_t bytes) {
        char* p = ws + off;
        off = (off + bytes + 255) & ~(size_t)255;
        return p;
    };
    unsigned short* y     = (unsigned short*)take((size_t)N * D * 2);
    unsigned short* Wb    = (unsigned short*)take((size_t)WE * 2);
    int* bucket           = (int*)take((size_t)E * 4);
    unsigned short* ghist = (unsigned short*)take((size_t)NBLK * N * 2);
    int* gbase            = (int*)take((size_t)NBLK * N * 4);
    int* offsets          = (int*)take((size_t)(N + 1) * 4);
    int* psum             = (int*)take(64 * 4);
    int* flag             = (int*)take(4);

    int nb256 = (N + 255) / 256;                 // scan blocks (<= 64)
    int xwb = (((N + 15) / 16) + 3) / 4;         // xw blocks (4 waves each)
    int wconv = (WE + 1023) / 1024;              // W-convert blocks

    k_prep<<<1 + wconv, 256, 0, stream>>>((const unsigned int*)srcv, flag, W, Wb, WE);
    k_fused<<<xwb + NBLK, 256, 0, stream>>>(x, Wb, y, N, xwb, dstv, flag, ghist, E, C);
    k_colsum<<<nb256, 256, 0, stream>>>(ghist, offsets, psum, N);
    k_pscan<<<1, 64, 0, stream>>>(psum, offsets, nb256, N, E);
    k_colbase<<<nb256, 256, 0, stream>>>(ghist, gbase, offsets, psum, N);
    k_scatter<<<NBLK, 1024, 0, stream>>>(srcv, dstv, flag, gbase, bucket, E, N, C);
    k_gather<<<(N + 3) / 4, 256, 0, stream>>>(y, offsets, bucket, b, out, N, E);
}